// Round 2
// baseline (44.207 us; speedup 1.0000x reference)
//
#include <hip/hip_runtime.h>

typedef __attribute__((ext_vector_type(8))) short bf16x8;
typedef __attribute__((ext_vector_type(4))) float f32x4;

constexpr int KPK = 2304;   // packed K: 36 blocks of 8x8 (f<=g), no padding needed
constexpr int QK  = 576;    // K per quarter (9 blocks)
constexpr int NROUND = 9;   // 8x8-blocks per quarter

__device__ __forceinline__ unsigned short bf_rne(float f) {
  unsigned u = __float_as_uint(f);
  return (unsigned short)((u + 0x7fffu + ((u >> 16) & 1u)) >> 16);
}

// ---- prepass: symmetrized packed bf16 Wp[o][KPK] ----
// quarter kq holds G-runs {G=7-kq, F=0..7-kq} then {G=kq, F=0..kq} (9 blocks).
// off-diagonal blocks (F!=G): value = W[f][g] + W[g][f]; diagonal: raw W[f][g].
__global__ __launch_bounds__(256) void wprep_kernel(const float* __restrict__ W,
                                                    unsigned short* __restrict__ Wp) {
  int e = blockIdx.x * 256 + threadIdx.x;   // 576 blocks * 256 = 147456 = 64*2304
  int o = e / KPK;
  int k = e - o * KPK;
  int kq = k / QK;
  int r = k - kq * QK;
  int j = r >> 6, i = r & 63;
  int run1 = 8 - kq;
  int G, F;
  if (j < run1) { G = 7 - kq; F = j; } else { G = kq; F = j - run1; }
  int f = F * 8 + (i >> 3), g = G * 8 + (i & 7);
  float v = W[o * 4096 + f * 64 + g];
  if (F != G) v += W[o * 4096 + g * 64 + f];
  Wp[o * KPK + k] = bf_rne(v);
}

// ---- main fused kernel: 256 blocks x 512 thr; wave = (pixel-half ph, K-quarter kq) ----
__global__ __launch_bounds__(512) void quad_kernel(const float* __restrict__ x,
                                                   const unsigned short* __restrict__ Wp,
                                                   float* __restrict__ out) {
  __shared__ alignas(16) unsigned short Ws[2][4][4096];   // [buf][quarter][64o x 64i] = 64 KB

  const int t = threadIdx.x;
  const int lane = t & 63;
  const int wv = t >> 6;        // 0..7
  const int kq = wv & 3;        // K quarter
  const int ph = wv >> 2;       // pixel half
  const int q = lane >> 4;      // k-slice 0..3
  const int r16 = lane & 15;
  const int pxbase = blockIdx.x * 128 + ph * 64;

  // stage round j (one 8x8-block per quarter, 4x8KB = 32 KB) into Ws[buf].
  // LDS dest linear; global source pre-swizzled (byte ^ (o&7)<<4) -> both-sides swizzle.
  auto stage = [&](int j, int buf) {
    const int o = t >> 3;
    const int ib = (t & 7) * 16;
    const char* src0 = reinterpret_cast<const char*>(Wp) + o * (KPK * 2) + j * 128 +
                       (ib ^ ((o & 7) << 4));
    char* dst0 = reinterpret_cast<char*>(&Ws[buf][0][0]) + wv * 1024;
#pragma unroll
    for (int c = 0; c < 4; ++c) {   // c = quarter area
      __builtin_amdgcn_global_load_lds(
          (const __attribute__((address_space(1))) void*)(src0 + c * (QK * 2)),
          (__attribute__((address_space(3))) void*)(dst0 + c * 8192), 16, 0, 0);
    }
  };

  stage(0, 0);

  int rowb[4];
#pragma unroll
  for (int m = 0; m < 4; ++m) rowb[m] = (pxbase + m * 16 + r16) * 64;

  const int run1 = 8 - kq;
  float xg[4][8];
  auto load_xg = [&](int G) {
#pragma unroll
    for (int m = 0; m < 4; ++m) {
      float4 a = *reinterpret_cast<const float4*>(x + rowb[m] + G * 8);
      float4 b = *reinterpret_cast<const float4*>(x + rowb[m] + G * 8 + 4);
      xg[m][0] = a.x; xg[m][1] = a.y; xg[m][2] = a.z; xg[m][3] = a.w;
      xg[m][4] = b.x; xg[m][5] = b.y; xg[m][6] = b.z; xg[m][7] = b.w;
    }
  };
  load_xg(7 - kq);

  f32x4 acc[4][4] = {};   // [m 4x16px][nt 4x16o]

  int buf = 0;
  for (int j = 0; j < NROUND; ++j) {
    __syncthreads();                       // drains stage(j); frees Ws[buf^1]
    if (j + 1 < NROUND) stage(j + 1, buf ^ 1);
    const int F = (j < run1) ? j : j - run1;
    if (j == run1) load_xg(kq);            // switch to second G-run

    float xf[4][2];
#pragma unroll
    for (int m = 0; m < 4; ++m)
#pragma unroll
      for (int s = 0; s < 2; ++s)
        xf[m][s] = x[rowb[m] + F * 8 + s * 4 + q];

    const char* wsb = reinterpret_cast<const char*>(&Ws[buf][kq][0]);
#pragma unroll
    for (int s = 0; s < 2; ++s) {
      bf16x8 afr[4];
#pragma unroll
      for (int m = 0; m < 4; ++m) {
        union { unsigned u[4]; bf16x8 v; } pk;
#pragma unroll
        for (int i = 0; i < 4; ++i) {
          unsigned p0 = __float_as_uint(xf[m][s] * xg[m][2 * i]);
          unsigned p1 = __float_as_uint(xf[m][s] * xg[m][2 * i + 1]);
          pk.u[i] = __builtin_amdgcn_perm(p1, p0, 0x07060302u);   // truncate-pack 2x bf16
        }
        afr[m] = pk.v;
      }
#pragma unroll
      for (int nt = 0; nt < 4; ++nt) {
        int o = nt * 16 + r16;
        bf16x8 bfr = *reinterpret_cast<const bf16x8*>(
            wsb + o * 128 + ((s * 64 + q * 16) ^ ((o & 7) << 4)));
#pragma unroll
        for (int m = 0; m < 4; ++m)
          acc[m][nt] = __builtin_amdgcn_mfma_f32_16x16x32_bf16(afr[m], bfr, acc[m][nt], 0, 0, 0);
      }
    }
    buf ^= 1;
  }

  // ---- K-quarter reduction via LDS (stride 68 -> 2-way banks, free) ----
  __syncthreads();
  float* red = reinterpret_cast<float*>(&Ws[0][0][0]);
  float* area = red + ph * (64 * 68);

  auto wr = [&]() {
#pragma unroll
    for (int m = 0; m < 4; ++m)
#pragma unroll
      for (int nt = 0; nt < 4; ++nt)
#pragma unroll
        for (int b = 0; b < 4; ++b)
          area[(m * 16 + q * 4 + b) * 68 + nt * 16 + r16] = acc[m][nt][b];
  };
  auto rd = [&]() {
#pragma unroll
    for (int m = 0; m < 4; ++m)
#pragma unroll
      for (int nt = 0; nt < 4; ++nt)
#pragma unroll
        for (int b = 0; b < 4; ++b)
          acc[m][nt][b] += area[(m * 16 + q * 4 + b) * 68 + nt * 16 + r16];
  };

  if (kq == 1) wr();
  __syncthreads();
  if (kq == 0) rd();
  __syncthreads();
  if (kq == 2) wr();
  __syncthreads();
  if (kq == 0) rd();
  __syncthreads();
  if (kq == 3) wr();
  __syncthreads();
  if (kq == 0) {
    rd();
    // D layout: row = q*4 + b, col = r16 (verified round 1)
#pragma unroll
    for (int m = 0; m < 4; ++m)
#pragma unroll
      for (int nt = 0; nt < 4; ++nt)
#pragma unroll
        for (int b = 0; b < 4; ++b)
          out[(long)(pxbase + m * 16 + q * 4 + b) * 64 + nt * 16 + r16] = acc[m][nt][b];
  }
}

extern "C" void kernel_launch(void* const* d_in, const int* in_sizes, int n_in,
                              void* d_out, int out_size, void* d_ws, size_t ws_size,
                              hipStream_t stream) {
  const float* x = (const float*)d_in[0];
  const float* W = (const float*)d_in[1];
  float* out = (float*)d_out;
  unsigned short* Wp = (unsigned short*)d_ws;   // 288 KB packed bf16 W

  hipLaunchKernelGGL(wprep_kernel, dim3(576), dim3(256), 0, stream, W, Wp);
  hipLaunchKernelGGL(quad_kernel, dim3(256), dim3(512), 0, stream, x, Wp, out);
}

// Round 3
// 25.908 us; speedup vs baseline: 1.7063x; 1.7063x over previous
//
#include <hip/hip_runtime.h>

typedef __attribute__((ext_vector_type(8))) short bf16x8;
typedef __attribute__((ext_vector_type(4))) float f32x4;

constexpr int KPK = 2304;   // packed K: 36 blocks of 8x8 (f<=g)
constexpr int QK  = 576;    // K per quarter (9 blocks)
constexpr int NROUND = 9;

__device__ __forceinline__ unsigned short bf_rne(float f) {
  unsigned u = __float_as_uint(f);
  return (unsigned short)((u + 0x7fffu + ((u >> 16) & 1u)) >> 16);
}

// ---- prepass: symmetrized packed bf16 Wp[o][KPK] (unchanged from round 2, verified) ----
__global__ __launch_bounds__(256) void wprep_kernel(const float* __restrict__ W,
                                                    unsigned short* __restrict__ Wp) {
  int e = blockIdx.x * 256 + threadIdx.x;   // 576*256 = 147456 = 64*2304
  int o = e / KPK;
  int k = e - o * KPK;
  int kq = k / QK;
  int r = k - kq * QK;
  int j = r >> 6, i = r & 63;
  int run1 = 8 - kq;
  int G, F;
  if (j < run1) { G = 7 - kq; F = j; } else { G = kq; F = j - run1; }
  int f = F * 8 + (i >> 3), g = G * 8 + (i & 7);
  float v = W[o * 4096 + f * 64 + g];
  if (F != G) v += W[o * 4096 + g * 64 + f];
  Wp[o * KPK + k] = bf_rne(v);
}

// ---- main: 512 blocks x 256 thr (4 waves = 4 K-quarters), 64 px/block, 80KB LDS ----
__global__ __launch_bounds__(256, 2) void quad_kernel(const float* __restrict__ x,
                                                      const unsigned short* __restrict__ Wp,
                                                      float* __restrict__ out) {
  __shared__ alignas(16) unsigned short Ws[2][4][4096];   // W dbuf: [buf][quarter][64o x 64k] = 64 KB
  __shared__ alignas(16) float xT[4096];                  // x tile, swizzled [f][px ^ f] = 16 KB

  const int t = threadIdx.x;
  const int lane = t & 63;
  const int kq = t >> 6;        // wave id = K quarter
  const int q = lane >> 4;      // k-slice 0..3
  const int r16 = lane & 15;
  const int pxbase = blockIdx.x * 64;

  // stage round j (32 KB: 4 quarters x 64o x 128B) into Ws[buf].
  // LDS dest linear; global source pre-swizzled with byte ^ ((o&7)<<4) (both-sides swizzle).
  auto stage = [&](int j, int buf) {
    char* ldsbase = reinterpret_cast<char*>(&Ws[buf][0][0]) + kq * 1024;
    const char* wp = reinterpret_cast<const char*>(Wp) + j * 128;
    const int o0 = t >> 3;
    const int o1 = 32 + o0;
    const int ib = (t & 7) * 16;
    const int s0 = o0 * 4608 + (ib ^ ((o0 & 7) << 4));
    const int s1 = o1 * 4608 + (ib ^ ((o1 & 7) << 4));
#pragma unroll
    for (int i = 0; i < 8; ++i) {
      int src_off = ((i & 1) ? s1 : s0) + (i >> 1) * 1152;   // quarter stride = QK*2
      __builtin_amdgcn_global_load_lds(
          (const __attribute__((address_space(1))) void*)(wp + src_off),
          (__attribute__((address_space(3))) void*)(ldsbase + i * 4096), 16, 0, 0);
    }
  };

  stage(0, 0);   // W round-0 loads fly under the x-staging below

  // x tile -> xT (transposed, XOR-swizzled; write conflicts 2-way = free)
  {
    const float* xg_ = x + (long)pxbase * 64;
#pragma unroll
    for (int c = 0; c < 4; ++c) {
      int e = c * 256 + t;
      int px = e >> 4;
      int f0 = (e & 15) * 4;
      float4 v = *reinterpret_cast<const float4*>(xg_ + px * 64 + f0);
      xT[(f0 + 0) * 64 + (px ^ (f0 + 0))] = v.x;
      xT[(f0 + 1) * 64 + (px ^ (f0 + 1))] = v.y;
      xT[(f0 + 2) * 64 + (px ^ (f0 + 2))] = v.z;
      xT[(f0 + 3) * 64 + (px ^ (f0 + 3))] = v.w;
    }
  }
  __syncthreads();   // xT ready; stage(0) drained (vmcnt)

  // per-lane g-chunk registers (conflict-free swizzled broadcast reads)
  float xg[4][8];
  auto load_xg = [&](int G) {
#pragma unroll
    for (int m = 0; m < 4; ++m) {
      int px = m * 16 + r16;
#pragma unroll
      for (int b = 0; b < 8; ++b) {
        int row = G * 8 + b;
        xg[m][b] = xT[row * 64 + (px ^ row)];
      }
    }
  };
  const int run1 = 8 - kq;
  load_xg(7 - kq);

  f32x4 acc[4][4] = {};   // [m: 4x16 px][nt: 4x16 o]
  int buf = 0;
  for (int j = 0; j < NROUND; ++j) {
    if (j) __syncthreads();              // drains stage(j); frees Ws[buf^1]
    if (j + 1 < NROUND) stage(j + 1, buf ^ 1);
    const int F = (j < run1) ? j : j - run1;
    if (j == run1) load_xg(kq);          // second G-run (xT still resident)

    float xf[4][2];
#pragma unroll
    for (int m = 0; m < 4; ++m) {
      int px = m * 16 + r16;
#pragma unroll
      for (int s = 0; s < 2; ++s) {
        int row = F * 8 + s * 4 + q;
        xf[m][s] = xT[row * 64 + (px ^ row)];
      }
    }

    const char* wsb = reinterpret_cast<const char*>(&Ws[buf][kq][0]);
#pragma unroll
    for (int s = 0; s < 2; ++s) {
      bf16x8 afr[4];
#pragma unroll
      for (int m = 0; m < 4; ++m) {
        union { unsigned u[4]; bf16x8 v; } pk;
#pragma unroll
        for (int i = 0; i < 4; ++i) {
          unsigned p0 = __float_as_uint(xf[m][s] * xg[m][2 * i]);
          unsigned p1 = __float_as_uint(xf[m][s] * xg[m][2 * i + 1]);
          pk.u[i] = __builtin_amdgcn_perm(p1, p0, 0x07060302u);   // truncate-pack 2x bf16
        }
        afr[m] = pk.v;
      }
#pragma unroll
      for (int nt = 0; nt < 4; ++nt) {
        int o = nt * 16 + r16;
        bf16x8 bfr = *reinterpret_cast<const bf16x8*>(
            wsb + o * 128 + ((s * 64 + q * 16) ^ ((o & 7) << 4)));
#pragma unroll
        for (int m = 0; m < 4; ++m)
          acc[m][nt] = __builtin_amdgcn_mfma_f32_16x16x32_bf16(afr[m], bfr, acc[m][nt], 0, 0, 0);
      }
    }
    buf ^= 1;
  }

  // ---- cross-wave K reduction in LDS: red[m][w][ [o 64][px 16] ] = 64 KB (reuses Ws) ----
  __syncthreads();
  float* red = reinterpret_cast<float*>(&Ws[0][0][0]);
#pragma unroll
  for (int m = 0; m < 4; ++m) {
#pragma unroll
    for (int nt = 0; nt < 4; ++nt) {
      // b128 writes: 8 lanes per 4-bank span, perfectly spread = throughput-optimal
      *reinterpret_cast<f32x4*>(red + (m * 4 + kq) * 1024 + (nt * 16 + r16) * 16 + q * 4) =
          acc[m][nt];
    }
  }
  __syncthreads();
  {
    const float* base = red + kq * 4 * 1024;   // wave kq owns m-tile kq
#pragma unroll
    for (int nt = 0; nt < 4; ++nt) {
      int off = (nt * 16 + r16) * 16 + q * 4;
      f32x4 ssum = *reinterpret_cast<const f32x4*>(base + off);
#pragma unroll
      for (int w = 1; w < 4; ++w)
        ssum += *reinterpret_cast<const f32x4*>(base + w * 1024 + off);
      long prow = pxbase + kq * 16 + q * 4;    // D layout: row = q*4+b, col = r16
#pragma unroll
      for (int b = 0; b < 4; ++b)
        out[(prow + b) * 64 + nt * 16 + r16] = ssum[b];
    }
  }
}

extern "C" void kernel_launch(void* const* d_in, const int* in_sizes, int n_in,
                              void* d_out, int out_size, void* d_ws, size_t ws_size,
                              hipStream_t stream) {
  const float* x = (const float*)d_in[0];
  const float* W = (const float*)d_in[1];
  float* out = (float*)d_out;
  unsigned short* Wp = (unsigned short*)d_ws;   // 288 KB packed bf16 W

  hipLaunchKernelGGL(wprep_kernel, dim3(576), dim3(256), 0, stream, W, Wp);
  hipLaunchKernelGGL(quad_kernel, dim3(512), dim3(256), 0, stream, x, Wp, out);
}